// Round 1
// baseline (289.136 us; speedup 1.0000x reference)
//
#include <hip/hip_runtime.h>
#include <hip/hip_bf16.h>
#include <stdint.h>

#define B_   64
#define N_   256
#define D_   1024
#define P_   2000
#define C_   200
#define PP   2048            // P padded to a multiple of 128
#define M_   (B_ * N_)       // 16384
#define EPSA 1e-4f

using f32x4  = __attribute__((ext_vector_type(4))) float;
using bf16x8 = __attribute__((ext_vector_type(8))) short;

__device__ __forceinline__ unsigned short f2bf(float f) {
  uint32_t u = __builtin_bit_cast(uint32_t, f);
  uint32_t r = (u + 0x7FFFu + ((u >> 16) & 1u)) >> 16;   // RNE; inputs finite
  return (unsigned short)r;
}

// ---------------------------------------------------------------------------
// Kernel 1: f32 -> bf16 conversion + row squared-norms (x2 for patches, p2 for
// prototypes). One 256-thread block per row of 1024 elements (4 per thread).
// Rows [0, M_) = patches; rows [M_, M_+PP) = prototypes (>=P_ are zero pad).
// ---------------------------------------------------------------------------
__global__ __launch_bounds__(256) void k_convert(
    const float* __restrict__ patches, const float* __restrict__ protos,
    unsigned short* __restrict__ pat_bf, unsigned short* __restrict__ pro_bf,
    float* __restrict__ x2, float* __restrict__ p2)
{
  const int row = blockIdx.x;
  const int t   = threadIdx.x;
  float4 v = make_float4(0.f, 0.f, 0.f, 0.f);
  if (row < M_) {
    v = *(const float4*)(patches + (size_t)row * D_ + t * 4);
  } else {
    const int p = row - M_;
    if (p < P_) v = *(const float4*)(protos + (size_t)p * D_ + t * 4);
  }
  ushort4 o;
  o.x = f2bf(v.x); o.y = f2bf(v.y); o.z = f2bf(v.z); o.w = f2bf(v.w);
  if (row < M_) *(ushort4*)(pat_bf + (size_t)row * D_ + t * 4) = o;
  else          *(ushort4*)(pro_bf + (size_t)(row - M_) * D_ + t * 4) = o;

  float s = v.x * v.x + v.y * v.y + v.z * v.z + v.w * v.w;
  #pragma unroll
  for (int off = 32; off >= 1; off >>= 1) s += __shfl_xor(s, off);
  __shared__ float sm[4];
  if ((t & 63) == 0) sm[t >> 6] = s;
  __syncthreads();
  if (t == 0) {
    const float tot = sm[0] + sm[1] + sm[2] + sm[3];
    if (row < M_) x2[row] = tot;
    else          p2[row - M_] = tot;          // pad rows get 0
  }
}

// ---------------------------------------------------------------------------
// Kernel 2: dist^T GEMM. Output tile rows = p (prototypes), cols = m (=b*256+n)
// so the MFMA C-layout (col = lane&15) is the n axis -> coalesced 64B store
// segments into attn[b][p][n]. 128x128 tile, BK=64, 4 waves (2p x 2n), each
// wave 64x64 via 4x4 fragments of v_mfma_f32_16x16x32_bf16.
// LDS staged with global_load_lds width-16; XOR slot swizzle (slot ^= row&7)
// applied on the *global source* (linear LDS dest) and again on ds_read.
// ---------------------------------------------------------------------------
__global__ __launch_bounds__(256) void k_gemm(
    const unsigned short* __restrict__ pro_bf,
    const unsigned short* __restrict__ pat_bf,
    const float* __restrict__ x2, const float* __restrict__ p2,
    float* __restrict__ attn)
{
  __shared__ unsigned short ldsA[128 * 64];   // prototypes tile [p][k]
  __shared__ unsigned short ldsB[128 * 64];   // patches    tile [m][k]

  const int tid  = threadIdx.x;
  const int lane = tid & 63;
  const int wid  = tid >> 6;
  const int wp   = wid >> 1;          // wave p-quadrant (0..1)
  const int wn   = wid & 1;           // wave n-quadrant (0..1)
  const int m0   = blockIdx.x * 128;  // patch-row tile base
  const int p0   = blockIdx.y * 128;  // prototype tile base (padded space)

  f32x4 acc[4][4];
  #pragma unroll
  for (int i = 0; i < 4; i++)
    #pragma unroll
    for (int j = 0; j < 4; j++) acc[i][j] = (f32x4){0.f, 0.f, 0.f, 0.f};

  // staging geometry: wave w covers rows [w*32, w*32+32), 4 instrs of 8 rows
  const int srowlane = lane >> 3;     // row within 8-row group
  const int sslot    = lane & 7;      // 16B slot within 128B row

  for (int kt = 0; kt < D_ / 64; ++kt) {
    const unsigned short* gA = pro_bf + (size_t)p0 * D_ + kt * 64;
    const unsigned short* gB = pat_bf + (size_t)m0 * D_ + kt * 64;
    #pragma unroll
    for (int i = 0; i < 4; i++) {
      const int r  = wid * 32 + i * 8 + srowlane;
      const int sl = sslot ^ (r & 7);              // inverse swizzle on source
      __builtin_amdgcn_global_load_lds(
          (const __attribute__((address_space(1))) void*)(gA + (size_t)r * D_ + sl * 8),
          (__attribute__((address_space(3))) void*)&ldsA[(wid * 32 + i * 8) * 64],
          16, 0, 0);
      __builtin_amdgcn_global_load_lds(
          (const __attribute__((address_space(1))) void*)(gB + (size_t)r * D_ + sl * 8),
          (__attribute__((address_space(3))) void*)&ldsB[(wid * 32 + i * 8) * 64],
          16, 0, 0);
    }
    __syncthreads();

    #pragma unroll
    for (int kk = 0; kk < 2; ++kk) {
      bf16x8 af[4], bfr[4];
      #pragma unroll
      for (int i = 0; i < 4; i++) {
        const int rA  = wp * 64 + i * 16 + (lane & 15);
        const int slA = (kk * 4 + (lane >> 4)) ^ (rA & 7);
        af[i] = *(const bf16x8*)&ldsA[rA * 64 + slA * 8];
        const int rB  = wn * 64 + i * 16 + (lane & 15);
        const int slB = (kk * 4 + (lane >> 4)) ^ (rB & 7);
        bfr[i] = *(const bf16x8*)&ldsB[rB * 64 + slB * 8];
      }
      #pragma unroll
      for (int i = 0; i < 4; i++)
        #pragma unroll
        for (int j = 0; j < 4; j++)
          acc[i][j] = __builtin_amdgcn_mfma_f32_16x16x32_bf16(
              af[i], bfr[j], acc[i][j], 0, 0, 0);
    }
    __syncthreads();
  }

  // epilogue: dist = relu(x2[m] + p2[p] - 2*dot); store attn[b][p][n]
  const int b = m0 >> 8;
  float* attn_b = attn + (size_t)b * (P_ * N_);
  float x2v[4]; int nn[4];
  #pragma unroll
  for (int j = 0; j < 4; j++) {
    const int m = m0 + wn * 64 + j * 16 + (lane & 15);
    x2v[j] = x2[m];
    nn[j]  = m & 255;
  }
  #pragma unroll
  for (int i = 0; i < 4; i++) {
    #pragma unroll
    for (int q = 0; q < 4; q++) {
      const int p = p0 + wp * 64 + i * 16 + (lane >> 4) * 4 + q;
      if (p < P_) {
        const float p2v = p2[p];
        float* rowp = attn_b + (size_t)p * N_;
        #pragma unroll
        for (int j = 0; j < 4; j++) {
          const float d = x2v[j] + p2v - 2.0f * acc[i][j][q];
          rowp[nn[j]] = fmaxf(d, 0.f);
        }
      }
    }
  }
}

// ---------------------------------------------------------------------------
// Kernel 3: min over n (256 contiguous floats) per (b,p); one wave each.
// Also computes the log activation for the logits GEMM.
// ---------------------------------------------------------------------------
__global__ __launch_bounds__(256) void k_min(
    const float* __restrict__ attn, float* __restrict__ min_out,
    float* __restrict__ act)
{
  const int gw   = (blockIdx.x * 256 + threadIdx.x) >> 6;  // (b*P_+p)
  const int lane = threadIdx.x & 63;
  const float4 v = ((const float4*)(attn + (size_t)gw * N_))[lane];
  float m = fminf(fminf(v.x, v.y), fminf(v.z, v.w));
  #pragma unroll
  for (int off = 32; off >= 1; off >>= 1) m = fminf(m, __shfl_xor(m, off));
  if (lane == 0) {
    min_out[gw] = m;
    act[gw] = logf((m + 1.0f) / (m + EPSA));
  }
}

// ---------------------------------------------------------------------------
// Kernel 4: logits[b][c] = sum_p act[b,p] * fc_w[c,p]; one wave per (b,c).
// ---------------------------------------------------------------------------
__global__ __launch_bounds__(256) void k_logits(
    const float* __restrict__ act, const float* __restrict__ fc_w,
    float* __restrict__ out)
{
  const int gw   = (blockIdx.x * 256 + threadIdx.x) >> 6;  // 0..12799
  const int lane = threadIdx.x & 63;
  const int b = gw & 63;
  const int c = gw >> 6;
  const float* a = act  + (size_t)b * P_;
  const float* w = fc_w + (size_t)c * P_;
  float s = 0.f;
  #pragma unroll
  for (int i = 0; i < 32; i++) {
    const int p = i * 64 + lane;
    if (p < P_) s += a[p] * w[p];
  }
  #pragma unroll
  for (int off = 32; off >= 1; off >>= 1) s += __shfl_xor(s, off);
  if (lane == 0) out[b * C_ + c] = s;
}

// ---------------------------------------------------------------------------
extern "C" void kernel_launch(void* const* d_in, const int* in_sizes, int n_in,
                              void* d_out, int out_size, void* d_ws, size_t ws_size,
                              hipStream_t stream)
{
  const float* patches = (const float*)d_in[0];
  const float* protos  = (const float*)d_in[1];
  const float* fc_w    = (const float*)d_in[2];

  float* out    = (float*)d_out;
  float* logits = out;                                  // [64*200]
  float* attn   = out + (size_t)B_ * C_;                // [64*2000*256]
  float* minv   = out + (size_t)B_ * C_ + (size_t)B_ * P_ * N_;

  char* ws = (char*)d_ws;
  unsigned short* pat_bf = (unsigned short*)ws;  ws += (size_t)M_ * D_ * 2;  // 33.6 MB
  unsigned short* pro_bf = (unsigned short*)ws;  ws += (size_t)PP * D_ * 2;  //  4.2 MB
  float* x2  = (float*)ws;                       ws += (size_t)M_ * 4;
  float* p2  = (float*)ws;                       ws += (size_t)PP * 4;
  float* act = (float*)ws;                                                   // 512 KB

  hipLaunchKernelGGL(k_convert, dim3(M_ + PP), dim3(256), 0, stream,
                     patches, protos, pat_bf, pro_bf, x2, p2);
  hipLaunchKernelGGL(k_gemm, dim3(M_ / 128, PP / 128), dim3(256), 0, stream,
                     pro_bf, pat_bf, x2, p2, attn);
  hipLaunchKernelGGL(k_min, dim3((B_ * P_) / 4), dim3(256), 0, stream,
                     attn, minv, act);
  hipLaunchKernelGGL(k_logits, dim3((B_ * C_) / 4), dim3(256), 0, stream,
                     act, fc_w, logits);
}

// Round 4
// 263.523 us; speedup vs baseline: 1.0972x; 1.0972x over previous
//
#include <hip/hip_runtime.h>
#include <hip/hip_bf16.h>
#include <stdint.h>

#define B_   64
#define N_   256
#define D_   1024
#define P_   2000
#define C_   200
#define PP   2048            // P padded to a multiple of 256
#define M_   (B_ * N_)       // 16384
#define EPSA 1e-4f

#define BM   256             // p rows per block
#define BN   256             // m cols per block (== N_, one full batch)
#define BK   64
#define NT   (D_ / BK)       // 16 K-tiles

using f32x4  = __attribute__((ext_vector_type(4))) float;
using bf16x8 = __attribute__((ext_vector_type(8))) short;

__device__ __forceinline__ unsigned short f2bf(float f) {
  uint32_t u = __builtin_bit_cast(uint32_t, f);
  uint32_t r = (u + 0x7FFFu + ((u >> 16) & 1u)) >> 16;   // RNE; inputs finite
  return (unsigned short)r;
}

// ---------------------------------------------------------------------------
// Kernel 1: f32 -> bf16 conversion + row squared-norms.
// ---------------------------------------------------------------------------
__global__ __launch_bounds__(256) void k_convert(
    const float* __restrict__ patches, const float* __restrict__ protos,
    unsigned short* __restrict__ pat_bf, unsigned short* __restrict__ pro_bf,
    float* __restrict__ x2, float* __restrict__ p2)
{
  const int row = blockIdx.x;
  const int t   = threadIdx.x;
  float4 v = make_float4(0.f, 0.f, 0.f, 0.f);
  if (row < M_) {
    v = *(const float4*)(patches + (size_t)row * D_ + t * 4);
  } else {
    const int p = row - M_;
    if (p < P_) v = *(const float4*)(protos + (size_t)p * D_ + t * 4);
  }
  ushort4 o;
  o.x = f2bf(v.x); o.y = f2bf(v.y); o.z = f2bf(v.z); o.w = f2bf(v.w);
  if (row < M_) *(ushort4*)(pat_bf + (size_t)row * D_ + t * 4) = o;
  else          *(ushort4*)(pro_bf + (size_t)(row - M_) * D_ + t * 4) = o;

  float s = v.x * v.x + v.y * v.y + v.z * v.z + v.w * v.w;
  #pragma unroll
  for (int off = 32; off >= 1; off >>= 1) s += __shfl_xor(s, off);
  __shared__ float sm[4];
  if ((t & 63) == 0) sm[t >> 6] = s;
  __syncthreads();
  if (t == 0) {
    const float tot = sm[0] + sm[1] + sm[2] + sm[3];
    if (row < M_) x2[row] = tot;
    else          p2[row - M_] = tot;          // pad rows get 0
  }
}

// ---------------------------------------------------------------------------
// Kernel 2: 256x256 8-phase dist^T GEMM with fused min + activation epilogue.
// rows = p (prototypes), cols = m (= b*256 + n); BN==N_ so one block sees the
// whole n-range of one batch -> complete min computed in-block.
// 8 waves (2 wr x 4 wc). Quadrant (ph,nh) reads A-half(ph), B-half(nh) only.
// Half-tile stage order per tile: h0=A0,h1=B0,h2=A1,h3=B1 (2 loads/wave each).
// vmcnt ledger (per wave, steady): boundary leaves {A1,B1}(t)=4 outstanding;
// q0 issues h0(t+1) [6], end vmcnt(4) confirms A1(t); q1 issues h1 [6], end
// vmcnt(4) confirms B1(t); q2 issues h2 [6], no wait; q3 issues h3 [8], end
// vmcnt(4) confirms {A0,B0}(t+1). Never drains to 0 until the tail tile.
// LDS = exactly 131072 B (the proven m201 size); wmin aliases the staging
// buffers after the final MFMA phase (separated by __syncthreads()).
// ---------------------------------------------------------------------------
#define VMW4 asm volatile("s_waitcnt vmcnt(4)" ::: "memory")
#define VMW2 asm volatile("s_waitcnt vmcnt(2)" ::: "memory")
#define VMW0 asm volatile("s_waitcnt vmcnt(0)" ::: "memory")
#define NOPW ((void)0)
#define BARR __builtin_amdgcn_s_barrier()

#define STAGE(KT, H, NB) do {                                                  \
  const int r0_ = ((H) >> 1) * 128;                                            \
  const unsigned short* gb_ = (((H) & 1) == 0)                                 \
      ? (pro_bf + (size_t)p0 * D_) : (pat_bf + (size_t)m0 * D_);               \
  unsigned short* lb_ = ((((H) & 1) == 0) ? ldsA : ldsB) + (NB) * (BM * BK);   \
  _Pragma("unroll")                                                            \
  for (int i_ = 0; i_ < 2; ++i_) {                                             \
    const int rr_  = r0_ + wid * 16 + i_ * 8;                                  \
    const int row_ = rr_ + (lane >> 3);                                        \
    const int sl_  = (lane & 7) ^ (row_ & 7);                                  \
    __builtin_amdgcn_global_load_lds(                                          \
      (const __attribute__((address_space(1))) void*)                          \
          (gb_ + (size_t)row_ * D_ + (KT) * BK + sl_ * 8),                     \
      (__attribute__((address_space(3))) void*)(lb_ + rr_ * BK), 16, 0, 0);    \
  }                                                                            \
} while (0)

#define PHASE(PH, NH, DOSTAGE, VMWAIT, DOBAR) do {                             \
  DOSTAGE;                                                                     \
  bf16x8 af_[4][2], bq_[2][2];                                                 \
  _Pragma("unroll")                                                            \
  for (int i_ = 0; i_ < 4; ++i_)                                               \
    _Pragma("unroll")                                                          \
    for (int kk_ = 0; kk_ < 2; ++kk_) {                                        \
      const int row_ = (PH) * 128 + wr * 64 + i_ * 16 + (lane & 15);           \
      const int sl_  = (kk_ * 4 + (lane >> 4)) ^ (row_ & 7);                   \
      af_[i_][kk_] = *(const bf16x8*)&ldsA[nb * (BM * BK) + row_ * BK + sl_ * 8];\
    }                                                                          \
  _Pragma("unroll")                                                            \
  for (int j_ = 0; j_ < 2; ++j_)                                               \
    _Pragma("unroll")                                                          \
    for (int kk_ = 0; kk_ < 2; ++kk_) {                                        \
      const int row_ = (NH) * 128 + wc * 32 + j_ * 16 + (lane & 15);           \
      const int sl_  = (kk_ * 4 + (lane >> 4)) ^ (row_ & 7);                   \
      bq_[j_][kk_] = *(const bf16x8*)&ldsB[nb * (BM * BK) + row_ * BK + sl_ * 8];\
    }                                                                          \
  __builtin_amdgcn_s_setprio(1);                                               \
  _Pragma("unroll")                                                            \
  for (int i_ = 0; i_ < 4; ++i_)                                               \
    _Pragma("unroll")                                                          \
    for (int j_ = 0; j_ < 2; ++j_)                                             \
      _Pragma("unroll")                                                        \
      for (int kk_ = 0; kk_ < 2; ++kk_)                                        \
        acc[(PH) * 4 + i_][(NH) * 2 + j_] =                                    \
            __builtin_amdgcn_mfma_f32_16x16x32_bf16(                           \
                af_[i_][kk_], bq_[j_][kk_],                                    \
                acc[(PH) * 4 + i_][(NH) * 2 + j_], 0, 0, 0);                   \
  __builtin_amdgcn_s_setprio(0);                                               \
  VMWAIT;                                                                      \
  __builtin_amdgcn_sched_barrier(0);                                           \
  DOBAR;                                                                       \
  __builtin_amdgcn_sched_barrier(0);                                           \
} while (0)

__global__ __launch_bounds__(512, 2) void k_gemm(
    const unsigned short* __restrict__ pro_bf,
    const unsigned short* __restrict__ pat_bf,
    const float* __restrict__ x2, const float* __restrict__ p2,
    float* __restrict__ attn, float* __restrict__ minv, float* __restrict__ act)
{
  extern __shared__ unsigned short lds_u16[];
  unsigned short* ldsA = lds_u16;                    // [2][256*64]
  unsigned short* ldsB = lds_u16 + 2 * BM * BK;      // [2][256*64]
  float* wmin = (float*)lds_u16;                     // aliases ldsA post-loop

  const int tid  = threadIdx.x;
  const int lane = tid & 63;
  const int wid  = tid >> 6;          // 0..7
  const int wr   = wid >> 2;          // 0..1 (p dim)
  const int wc   = wid & 3;           // 0..3 (n dim)

  // XCD-aware swizzle: XCD x gets m-tiles [x*8, x*8+8) x all 8 p-tiles.
  const int wg  = blockIdx.x;         // 0..511
  const int xcd = wg & 7;
  const int idx = wg >> 3;            // 0..63
  const int mt  = xcd * 8 + (idx & 7);
  const int pt  = idx >> 3;
  const int b   = mt;
  const int p0  = pt * BM;
  const int m0  = mt * BN;

  f32x4 acc[8][4];
  #pragma unroll
  for (int i = 0; i < 8; i++)
    #pragma unroll
    for (int j = 0; j < 4; j++) acc[i][j] = (f32x4){0.f, 0.f, 0.f, 0.f};

  // prologue: stage tile 0, confirm A0,B0
  STAGE(0, 0, 0); STAGE(0, 1, 0); STAGE(0, 2, 0); STAGE(0, 3, 0);
  VMW4;
  __builtin_amdgcn_sched_barrier(0);
  BARR;
  __builtin_amdgcn_sched_barrier(0);

  int nb = 0;
  #pragma unroll 1
  for (int kt = 0; kt < NT - 1; ++kt) {
    PHASE(0, 0, STAGE(kt + 1, 0, nb ^ 1), VMW4, BARR);
    PHASE(1, 0, STAGE(kt + 1, 1, nb ^ 1), VMW4, BARR);
    PHASE(1, 1, STAGE(kt + 1, 2, nb ^ 1), NOPW, BARR);
    PHASE(0, 1, STAGE(kt + 1, 3, nb ^ 1), VMW4, BARR);
    nb ^= 1;
  }
  // tail tile (NT-1): outstanding = {A1,B1} = 4 loads
  PHASE(0, 0, NOPW, VMW2, BARR);
  PHASE(1, 0, NOPW, VMW0, BARR);
  PHASE(1, 1, NOPW, NOPW, NOPW);
  PHASE(0, 1, NOPW, NOPW, NOPW);

  __syncthreads();   // staging LDS now dead; safe to alias as wmin

  // ---- epilogue: relu-dist store + fused min/activation --------------------
  float x2v[2][2]; int nn[2][2];
  #pragma unroll
  for (int nh = 0; nh < 2; ++nh)
    #pragma unroll
    for (int j = 0; j < 2; ++j) {
      const int nl = nh * 128 + wc * 32 + j * 16 + (lane & 15);
      x2v[nh][j] = x2[m0 + nl];
      nn[nh][j]  = nl;
    }
  float* attn_b = attn + (size_t)b * (P_ * N_);

  #pragma unroll
  for (int pf = 0; pf < 8; ++pf) {
    #pragma unroll
    for (int q = 0; q < 4; ++q) {
      const int pl = (pf >> 2) * 128 + wr * 64 + (pf & 3) * 16 + (lane >> 4) * 4 + q;
      const int p  = p0 + pl;
      float mn = 3.4e38f;
      if (p < P_) {
        const float p2v = p2[p];
        float* rowp = attn_b + (size_t)p * N_;
        #pragma unroll
        for (int nh = 0; nh < 2; ++nh)
          #pragma unroll
          for (int j = 0; j < 2; ++j) {
            const float d = fmaxf(x2v[nh][j] + p2v - 2.0f * acc[pf][nh * 2 + j][q], 0.f);
            rowp[nn[nh][j]] = d;
            mn = fminf(mn, d);
          }
      }
      #pragma unroll
      for (int mask = 1; mask <= 8; mask <<= 1) mn = fminf(mn, __shfl_xor(mn, mask));
      if ((lane & 15) == 0) wmin[wc * 256 + pl] = mn;
    }
  }
  __syncthreads();
  if (tid < 256) {
    const int p = p0 + tid;
    if (p < P_) {
      const float m = fminf(fminf(wmin[tid], wmin[256 + tid]),
                            fminf(wmin[512 + tid], wmin[768 + tid]));
      minv[b * P_ + p] = m;
      act[b * P_ + p]  = logf((m + 1.0f) / (m + EPSA));
    }
  }
}

// ---------------------------------------------------------------------------
// Kernel 3: logits[b][c] = sum_p act[b,p] * fc_w[c,p]; one wave per (b,c).
// ---------------------------------------------------------------------------
__global__ __launch_bounds__(256) void k_logits(
    const float* __restrict__ act, const float* __restrict__ fc_w,
    float* __restrict__ out)
{
  const int gw   = (blockIdx.x * 256 + threadIdx.x) >> 6;
  const int lane = threadIdx.x & 63;
  const int b = gw & 63;
  const int c = gw >> 6;
  const float* a = act  + (size_t)b * P_;
  const float* w = fc_w + (size_t)c * P_;
  float s = 0.f;
  #pragma unroll
  for (int i = 0; i < 32; i++) {
    const int p = i * 64 + lane;
    if (p < P_) s += a[p] * w[p];
  }
  #pragma unroll
  for (int off = 32; off >= 1; off >>= 1) s += __shfl_xor(s, off);
  if (lane == 0) out[b * C_ + c] = s;
}

// ---------------------------------------------------------------------------
#define GEMM_LDS_BYTES (4 * BM * BK * 2)   // exactly 128 KiB (m201-proven)

extern "C" void kernel_launch(void* const* d_in, const int* in_sizes, int n_in,
                              void* d_out, int out_size, void* d_ws, size_t ws_size,
                              hipStream_t stream)
{
  const float* patches = (const float*)d_in[0];
  const float* protos  = (const float*)d_in[1];
  const float* fc_w    = (const float*)d_in[2];

  float* out    = (float*)d_out;
  float* logits = out;
  float* attn   = out + (size_t)B_ * C_;
  float* minv   = out + (size_t)B_ * C_ + (size_t)B_ * P_ * N_;

  char* ws = (char*)d_ws;
  unsigned short* pat_bf = (unsigned short*)ws;  ws += (size_t)M_ * D_ * 2;
  unsigned short* pro_bf = (unsigned short*)ws;  ws += (size_t)PP * D_ * 2;
  float* x2  = (float*)ws;                       ws += (size_t)M_ * 4;
  float* p2  = (float*)ws;                       ws += (size_t)PP * 4;
  float* act = (float*)ws;

  (void)hipFuncSetAttribute((const void*)k_gemm,
                            hipFuncAttributeMaxDynamicSharedMemorySize,
                            GEMM_LDS_BYTES);

  hipLaunchKernelGGL(k_convert, dim3(M_ + PP), dim3(256), 0, stream,
                     patches, protos, pat_bf, pro_bf, x2, p2);
  hipLaunchKernelGGL(k_gemm, dim3((M_ / BN) * (PP / BM)), dim3(512),
                     GEMM_LDS_BYTES, stream,
                     pro_bf, pat_bf, x2, p2, attn, minv, act);
  hipLaunchKernelGGL(k_logits, dim3((B_ * C_) / 4), dim3(256), 0, stream,
                     act, fc_w, logits);
}